// Round 1
// 866.122 us; speedup vs baseline: 1.0591x; 1.0591x over previous
//
#include <hip/hip_runtime.h>
#include <hip/hip_bf16.h>

#define IN_C   128
#define HID    16
#define OUT_C  8
#define EDGE_C 16
#define NG     64
#define NRANGE 8   // dst ranges, pinned to XCDs via blockIdx % 8

// ---------------------------------------------------------------------------
__global__ void deg_kernel(const int* __restrict__ dst, int* __restrict__ deg, int E) {
    int e = blockIdx.x * blockDim.x + threadIdx.x;
    if (e < E) atomicAdd(&deg[dst[e]], 1);
}

// Exclusive scan stage A: per-256-block Hillis-Steele (writes exclusive-within-block)
__global__ void scanA_kernel(const int* __restrict__ deg, int* __restrict__ row_start,
                             int* __restrict__ blocksum, int n) {
    __shared__ int s[256];
    int t = threadIdx.x;
    int i = blockIdx.x * 256 + t;
    int own = (i < n) ? deg[i] : 0;
    s[t] = own; __syncthreads();
    for (int off = 1; off < 256; off <<= 1) {
        int v = (t >= off) ? s[t - off] : 0;
        __syncthreads();
        s[t] += v;
        __syncthreads();
    }
    if (i < n) row_start[i] = s[t] - own;
    if (t == 255) blocksum[blockIdx.x] = s[255];
}

__global__ void scanB_kernel(int* __restrict__ blocksum, int nb) {
    __shared__ int s[512];
    int t = threadIdx.x;
    int own = (t < nb) ? blocksum[t] : 0;
    s[t] = own; __syncthreads();
    for (int off = 1; off < 512; off <<= 1) {
        int v = (t >= off) ? s[t - off] : 0;
        __syncthreads();
        s[t] += v;
        __syncthreads();
    }
    if (t < nb) blocksum[t] = s[t] - own;
}

// row_start += blockoff (in place); cursor = row_start; dinv = rsqrt(deg+1)
__global__ void scanC_kernel(const int* __restrict__ deg, int* __restrict__ row_start,
                             const int* __restrict__ blocksum,
                             int* __restrict__ cursor, float* __restrict__ dinv, int n) {
    int i = blockIdx.x * 256 + threadIdx.x;
    if (i < n) {
        int rs = row_start[i] + blocksum[blockIdx.x];
        row_start[i] = rs;
        cursor[i] = rs;
        dinv[i] = rsqrtf((float)deg[i] + 1.0f);
    }
}

// XCD-pinned CSR fill: range r = blockIdx%8 owns dst in [r*rs, r*rs+rs).
__global__ void fill_kernel(const int* __restrict__ src, const int* __restrict__ dst,
                            int* __restrict__ cursor, int2* __restrict__ adj,
                            int E, int range_size, int bpr) {
    int r = blockIdx.x & (NRANGE - 1);
    int q = blockIdx.x >> 3;
    int lo = r * range_size;
    int hi = lo + range_size;
    long long chunk = ((long long)E + bpr - 1) / bpr;
    int e0 = (int)((long long)q * chunk);
    long long e1l = (long long)e0 + chunk;
    int e1 = (e1l < E) ? (int)e1l : E;
    for (int e = e0 + threadIdx.x; e < e1; e += blockDim.x) {
        int d = dst[e];
        if (d >= lo && d < hi) {
            int pos = atomicAdd(&cursor[d], 1);
            adj[pos] = make_int2(e, src[e]);
        }
    }
}

// a1[v][c] = dinv[v] * (x[v] @ W1_node)[c]
__global__ void xform1_kernel(const float* __restrict__ x, const float* __restrict__ W,
                              const float* __restrict__ dinv, float* __restrict__ a1, int n) {
    int t = threadIdx.x;
    int v = blockIdx.x * 16 + (t >> 4);
    int c = t & 15;
    if (v >= n) return;
    const float4* xr = (const float4*)(x + (size_t)v * IN_C);
    float acc = 0.0f;
#pragma unroll
    for (int k4 = 0; k4 < IN_C / 4; ++k4) {
        float4 xv = xr[k4];
        int k = k4 * 4;
        acc += xv.x * W[(k + 0) * HID + c];
        acc += xv.y * W[(k + 1) * HID + c];
        acc += xv.z * W[(k + 2) * HID + c];
        acc += xv.w * W[(k + 3) * HID + c];
    }
    a1[(size_t)v * HID + c] = dinv[v] * acc;
}

// Pass 1: wave per node, 4 edge-slots x 16 channels.
// MLP restructure: per 64-edge chunk, prefetch adj (COALESCED, lane i -> edge i)
// + dinv[src], then shfl-broadcast (e,s,ds) into the 16-lane channel groups.
// Gather addresses come from registers -> unrolled iterations issue many
// independent 64B row-gathers (edge_attr, a1) instead of a 2-deep chain.
__global__ void gather1_kernel(const int2* __restrict__ adj, const int* __restrict__ row_start,
                               const int* __restrict__ deg,
                               const float* __restrict__ edge_attr,
                               const float* __restrict__ W1e, const float* __restrict__ W2n,
                               const float* __restrict__ a1, const float* __restrict__ dinv,
                               float* __restrict__ a2, float* __restrict__ ES, int n) {
    int t = threadIdx.x;
    int lane = t & 63;
    int slot = lane >> 4;
    int c = lane & 15;
    float we[EDGE_C], wn[HID];
#pragma unroll
    for (int k = 0; k < EDGE_C; ++k) we[k] = W1e[k * HID + c];
#pragma unroll
    for (int k = 0; k < HID; ++k) wn[k] = W2n[k * HID + c];
    int v = blockIdx.x * 4 + (t >> 6);          // wave-uniform
    if (v >= n) return;
    int start = row_start[v];
    int dg = deg[v];
    float es = 0.0f, s1 = 0.0f;
    for (int base = 0; base < dg; base += 64) {
        int m = dg - base; if (m > 64) m = 64;
        int e_my = 0, s_my = 0;
        float ds_my = 0.0f;
        if (lane < m) {
            int2 ad = adj[start + base + lane];   // coalesced: one wait per 64 edges
            e_my = ad.x;
            s_my = ad.y;
            ds_my = dinv[s_my];                   // L2-resident (0.4 MB)
        }
#pragma unroll 4
        for (int i = slot; i < m; i += 4) {
            int e = __shfl(e_my, i, 64);
            int s = __shfl(s_my, i, 64);
            float ds = __shfl(ds_my, i, 64);
            es += ds * edge_attr[e * EDGE_C + c];   // 64B row, 16-lane coalesced
            s1 += a1[s * HID + c];                  // 64B row, L3-resident
        }
    }
    es += __shfl_xor(es, 16, 64); es += __shfl_xor(es, 32, 64);
    s1 += __shfl_xor(s1, 16, 64); s1 += __shfl_xor(s1, 32, 64);
    float dv = dinv[v];
    int lanebase = lane & ~15;
    float e1 = 0.0f;
#pragma unroll
    for (int k = 0; k < EDGE_C; ++k)
        e1 += __shfl(es, lanebase + k, 64) * we[k];
    float h = fmaxf(dv * (s1 + a1[(size_t)v * HID + c] + e1), 0.0f);
    float o = 0.0f;
#pragma unroll
    for (int k = 0; k < HID; ++k)
        o += __shfl(h, lanebase + k, 64) * wn[k];
    if (slot == 0) {
        a2[(size_t)v * HID + c] = dv * o;
        ES[(size_t)v * HID + c] = es;
    }
}

// Pass 2: neighbor-sum of a2 only (no edge_attr), same prefetch+broadcast scheme.
__global__ void gather2_kernel(const int2* __restrict__ adj, const int* __restrict__ row_start,
                               const int* __restrict__ deg,
                               const float* __restrict__ W2e,
                               const float* __restrict__ a2, const float* __restrict__ dinv,
                               const float* __restrict__ ES, float* __restrict__ h2, int n) {
    int t = threadIdx.x;
    int lane = t & 63;
    int slot = lane >> 4;
    int c = lane & 15;
    float we[EDGE_C];
#pragma unroll
    for (int k = 0; k < EDGE_C; ++k) we[k] = W2e[k * HID + c];
    int v = blockIdx.x * 4 + (t >> 6);
    if (v >= n) return;
    int start = row_start[v];
    int dg = deg[v];
    float s2 = 0.0f;
    for (int base = 0; base < dg; base += 64) {
        int m = dg - base; if (m > 64) m = 64;
        int s_my = 0;
        if (lane < m) s_my = adj[start + base + lane].y;   // coalesced prefetch
#pragma unroll 4
        for (int i = slot; i < m; i += 4) {
            int s = __shfl(s_my, i, 64);
            s2 += a2[s * HID + c];                          // L3-resident gather
        }
    }
    s2 += __shfl_xor(s2, 16, 64); s2 += __shfl_xor(s2, 32, 64);
    float dv = dinv[v];
    int lanebase = lane & ~15;
    float esv = ES[(size_t)v * HID + c];
    float e2 = 0.0f;
#pragma unroll
    for (int k = 0; k < EDGE_C; ++k)
        e2 += __shfl(esv, lanebase + k, 64) * we[k];
    float h = fmaxf(dv * (s2 + a2[(size_t)v * HID + c] + e2), 0.0f);
    if (slot == 0) h2[(size_t)v * HID + c] = h;
}

// One block per graph: binary-search sorted batch for [start,end), LDS-reduce, 16x8 head.
__global__ void pool_final_kernel(const float* __restrict__ h2,
                                  const int* __restrict__ batch,
                                  const float* __restrict__ W, const float* __restrict__ b,
                                  float* __restrict__ out, int n) {
    __shared__ float sdata[256];
    int g = blockIdx.x;
    int t = threadIdx.x;
    int c = t & 15;
    int lo = 0, hi = n;
    while (lo < hi) { int m = (lo + hi) >> 1; if (batch[m] < g) lo = m + 1; else hi = m; }
    int start = lo;
    hi = n;
    while (lo < hi) { int m = (lo + hi) >> 1; if (batch[m] < g + 1) lo = m + 1; else hi = m; }
    int end = lo;
    float acc = 0.0f;
    for (int v = start + (t >> 4); v < end; v += 16)
        acc += h2[(size_t)v * HID + c];
    sdata[t] = acc; __syncthreads();
    for (int s = 128; s >= 16; s >>= 1) {
        if (t < s) sdata[t] += sdata[t + s];
        __syncthreads();
    }
    if (t < OUT_C) {
        float inv = 1.0f / fmaxf((float)(end - start), 1.0f);
        float o = b[t];
#pragma unroll
        for (int cc = 0; cc < HID; ++cc)
            o += sdata[cc] * inv * W[cc * OUT_C + t];
        out[g * OUT_C + t] = o;
    }
}

// ---------------------------------------------------------------------------
extern "C" void kernel_launch(void* const* d_in, const int* in_sizes, int n_in,
                              void* d_out, int out_size, void* d_ws, size_t ws_size,
                              hipStream_t stream) {
    const float* x         = (const float*)d_in[0];
    const int*   edge_idx  = (const int*)d_in[1];
    const float* edge_attr = (const float*)d_in[2];
    const int*   batch     = (const int*)d_in[3];
    const float* W1_node   = (const float*)d_in[4];
    const float* W1_edge   = (const float*)d_in[5];
    const float* W2_node   = (const float*)d_in[6];
    const float* W2_edge   = (const float*)d_in[7];
    const float* node_W    = (const float*)d_in[8];
    const float* node_b    = (const float*)d_in[9];
    float* out = (float*)d_out;

    const int N = in_sizes[0] / IN_C;
    const int E = in_sizes[1] / 2;
    const int* src = edge_idx;
    const int* dst = edge_idx + E;

    // Workspace layout (adj first for 8B alignment):
    char* p = (char*)d_ws;
    int2*  adj       = (int2*)p;   p += sizeof(int2) * (size_t)E;
    int*   deg       = (int*)p;    p += sizeof(int) * (size_t)N;   // zeroed
    int*   row_start = (int*)p;    p += sizeof(int) * (size_t)N;
    int*   cursor    = (int*)p;    p += sizeof(int) * (size_t)N;
    int*   blocksum  = (int*)p;    p += sizeof(int) * 512;
    float* dinv      = (float*)p;  p += sizeof(float) * (size_t)N;
    float* a1        = (float*)p;  p += sizeof(float) * (size_t)HID * N;
    float* a2        = (float*)p;  p += sizeof(float) * (size_t)HID * N;
    float* ES        = (float*)p;  p += sizeof(float) * (size_t)HID * N;
    float* h2        = a1;         // a1 dead after gather1

    hipMemsetAsync(deg, 0, sizeof(int) * (size_t)N, stream);

    const int tb = 256;
    const int nbN = (N + 255) / 256;
    deg_kernel <<<(E + tb - 1) / tb, tb, 0, stream>>>(dst, deg, E);
    scanA_kernel<<<nbN, 256, 0, stream>>>(deg, row_start, blocksum, N);
    scanB_kernel<<<1, 512, 0, stream>>>(blocksum, nbN);
    scanC_kernel<<<nbN, 256, 0, stream>>>(deg, row_start, blocksum, cursor, dinv, N);

    const int range_size = (N + NRANGE - 1) / NRANGE;
    const int bpr = 128;                       // blocks per range -> 1024 blocks total
    fill_kernel<<<NRANGE * bpr, tb, 0, stream>>>(src, dst, cursor, adj, E, range_size, bpr);

    xform1_kernel<<<(N + 15) / 16, tb, 0, stream>>>(x, W1_node, dinv, a1, N);

    gather1_kernel<<<(N + 3) / 4, tb, 0, stream>>>(
        adj, row_start, deg, edge_attr, W1_edge, W2_node, a1, dinv, a2, ES, N);
    gather2_kernel<<<(N + 3) / 4, tb, 0, stream>>>(
        adj, row_start, deg, W2_edge, a2, dinv, ES, h2, N);

    pool_final_kernel<<<NG, 256, 0, stream>>>(h2, batch, node_W, node_b, out, N);
}

// Round 2
// 855.776 us; speedup vs baseline: 1.0719x; 1.0121x over previous
//
#include <hip/hip_runtime.h>
#include <hip/hip_bf16.h>

#define IN_C   128
#define HID    16
#define OUT_C  8
#define EDGE_C 16
#define NG     64
#define NRANGE 8   // dst ranges, pinned to XCDs via blockIdx % 8

// ---------------------------------------------------------------------------
__global__ void deg_kernel(const int* __restrict__ dst, int* __restrict__ deg, int E) {
    int e = blockIdx.x * blockDim.x + threadIdx.x;
    if (e < E) atomicAdd(&deg[dst[e]], 1);
}

// Exclusive scan stage A: per-256-block Hillis-Steele (writes exclusive-within-block)
__global__ void scanA_kernel(const int* __restrict__ deg, int* __restrict__ row_start,
                             int* __restrict__ blocksum, int n) {
    __shared__ int s[256];
    int t = threadIdx.x;
    int i = blockIdx.x * 256 + t;
    int own = (i < n) ? deg[i] : 0;
    s[t] = own; __syncthreads();
    for (int off = 1; off < 256; off <<= 1) {
        int v = (t >= off) ? s[t - off] : 0;
        __syncthreads();
        s[t] += v;
        __syncthreads();
    }
    if (i < n) row_start[i] = s[t] - own;
    if (t == 255) blocksum[blockIdx.x] = s[255];
}

__global__ void scanB_kernel(int* __restrict__ blocksum, int nb) {
    __shared__ int s[512];
    int t = threadIdx.x;
    int own = (t < nb) ? blocksum[t] : 0;
    s[t] = own; __syncthreads();
    for (int off = 1; off < 512; off <<= 1) {
        int v = (t >= off) ? s[t - off] : 0;
        __syncthreads();
        s[t] += v;
        __syncthreads();
    }
    if (t < nb) blocksum[t] = s[t] - own;
}

// row_start += blockoff (in place); cursor = row_start; dinv = rsqrt(deg+1)
__global__ void scanC_kernel(const int* __restrict__ deg, int* __restrict__ row_start,
                             const int* __restrict__ blocksum,
                             int* __restrict__ cursor, float* __restrict__ dinv, int n) {
    int i = blockIdx.x * 256 + threadIdx.x;
    if (i < n) {
        int rs = row_start[i] + blocksum[blockIdx.x];
        row_start[i] = rs;
        cursor[i] = rs;
        dinv[i] = rsqrtf((float)deg[i] + 1.0f);
    }
}

// XCD-pinned CSR fill: range r = blockIdx%8 owns dst in [r*rs, r*rs+rs).
// nt loads on dst/src: the streams must NOT evict partially-written adj lines
// from the XCD's L2 (they were causing 7x write amplification: 181MB vs 25.6).
__global__ void fill_kernel(const int* __restrict__ src, const int* __restrict__ dst,
                            int* __restrict__ cursor, int2* __restrict__ adj,
                            int E, int range_size, int bpr) {
    int r = blockIdx.x & (NRANGE - 1);
    int q = blockIdx.x >> 3;
    int lo = r * range_size;
    int hi = lo + range_size;
    long long chunk = ((long long)E + bpr - 1) / bpr;
    int e0 = (int)((long long)q * chunk);
    long long e1l = (long long)e0 + chunk;
    int e1 = (e1l < E) ? (int)e1l : E;
#pragma unroll 4
    for (int e = e0 + threadIdx.x; e < e1; e += blockDim.x) {
        int d = __builtin_nontemporal_load(dst + e);
        if (d >= lo && d < hi) {
            int s = __builtin_nontemporal_load(src + e);
            int pos = atomicAdd(&cursor[d], 1);
            adj[pos] = make_int2(e, s);
        }
    }
}

// a1[v][c] = dinv[v] * (x[v] @ W1_node)[c]
__global__ void xform1_kernel(const float* __restrict__ x, const float* __restrict__ W,
                              const float* __restrict__ dinv, float* __restrict__ a1, int n) {
    int t = threadIdx.x;
    int v = blockIdx.x * 16 + (t >> 4);
    int c = t & 15;
    if (v >= n) return;
    const float4* xr = (const float4*)(x + (size_t)v * IN_C);
    float acc = 0.0f;
#pragma unroll
    for (int k4 = 0; k4 < IN_C / 4; ++k4) {
        float4 xv = xr[k4];
        int k = k4 * 4;
        acc += xv.x * W[(k + 0) * HID + c];
        acc += xv.y * W[(k + 1) * HID + c];
        acc += xv.z * W[(k + 2) * HID + c];
        acc += xv.w * W[(k + 3) * HID + c];
    }
    a1[(size_t)v * HID + c] = dinv[v] * acc;
}

// Pass 1: wave per node, 4 edge-slots x 16 channels.
// Per 64-edge chunk, prefetch adj (COALESCED, nt: zero reuse) + dinv[src],
// then shfl-broadcast (e,s,ds) into the 16-lane channel groups.
// edge_attr rows also nt (each row read exactly once) so they don't evict
// the reused a1/dinv gather targets from L2.
__global__ void gather1_kernel(const int2* __restrict__ adj, const int* __restrict__ row_start,
                               const int* __restrict__ deg,
                               const float* __restrict__ edge_attr,
                               const float* __restrict__ W1e, const float* __restrict__ W2n,
                               const float* __restrict__ a1, const float* __restrict__ dinv,
                               float* __restrict__ a2, float* __restrict__ ES, int n) {
    int t = threadIdx.x;
    int lane = t & 63;
    int slot = lane >> 4;
    int c = lane & 15;
    float we[EDGE_C], wn[HID];
#pragma unroll
    for (int k = 0; k < EDGE_C; ++k) we[k] = W1e[k * HID + c];
#pragma unroll
    for (int k = 0; k < HID; ++k) wn[k] = W2n[k * HID + c];
    int v = blockIdx.x * 4 + (t >> 6);          // wave-uniform
    if (v >= n) return;
    int start = row_start[v];
    int dg = deg[v];
    float es = 0.0f, s1 = 0.0f;
    for (int base = 0; base < dg; base += 64) {
        int m = dg - base; if (m > 64) m = 64;
        int e_my = 0, s_my = 0;
        float ds_my = 0.0f;
        if (lane < m) {
            long long adv = __builtin_nontemporal_load(
                (const long long*)&adj[start + base + lane]);   // coalesced, stream
            e_my = (int)(adv & 0xffffffffLL);
            s_my = (int)(adv >> 32);
            ds_my = dinv[s_my];                   // L2-resident (0.4 MB)
        }
#pragma unroll 4
        for (int i = slot; i < m; i += 4) {
            int e = __shfl(e_my, i, 64);
            int s = __shfl(s_my, i, 64);
            float ds = __shfl(ds_my, i, 64);
            es += ds * __builtin_nontemporal_load(edge_attr + (size_t)e * EDGE_C + c);
            s1 += a1[s * HID + c];                  // reused (deg~32) -> cached
        }
    }
    es += __shfl_xor(es, 16, 64); es += __shfl_xor(es, 32, 64);
    s1 += __shfl_xor(s1, 16, 64); s1 += __shfl_xor(s1, 32, 64);
    float dv = dinv[v];
    int lanebase = lane & ~15;
    float e1 = 0.0f;
#pragma unroll
    for (int k = 0; k < EDGE_C; ++k)
        e1 += __shfl(es, lanebase + k, 64) * we[k];
    float h = fmaxf(dv * (s1 + a1[(size_t)v * HID + c] + e1), 0.0f);
    float o = 0.0f;
#pragma unroll
    for (int k = 0; k < HID; ++k)
        o += __shfl(h, lanebase + k, 64) * wn[k];
    if (slot == 0) {
        a2[(size_t)v * HID + c] = dv * o;
        ES[(size_t)v * HID + c] = es;
    }
}

// Pass 2: neighbor-sum of a2 only (no edge_attr), same prefetch+broadcast scheme.
__global__ void gather2_kernel(const int2* __restrict__ adj, const int* __restrict__ row_start,
                               const int* __restrict__ deg,
                               const float* __restrict__ W2e,
                               const float* __restrict__ a2, const float* __restrict__ dinv,
                               const float* __restrict__ ES, float* __restrict__ h2, int n) {
    int t = threadIdx.x;
    int lane = t & 63;
    int slot = lane >> 4;
    int c = lane & 15;
    float we[EDGE_C];
#pragma unroll
    for (int k = 0; k < EDGE_C; ++k) we[k] = W2e[k * HID + c];
    int v = blockIdx.x * 4 + (t >> 6);
    if (v >= n) return;
    int start = row_start[v];
    int dg = deg[v];
    float s2 = 0.0f;
    for (int base = 0; base < dg; base += 64) {
        int m = dg - base; if (m > 64) m = 64;
        int s_my = 0;
        if (lane < m) {
            long long adv = __builtin_nontemporal_load(
                (const long long*)&adj[start + base + lane]);
            s_my = (int)(adv >> 32);
        }
#pragma unroll 4
        for (int i = slot; i < m; i += 4) {
            int s = __shfl(s_my, i, 64);
            s2 += a2[s * HID + c];                          // reused -> cached
        }
    }
    s2 += __shfl_xor(s2, 16, 64); s2 += __shfl_xor(s2, 32, 64);
    float dv = dinv[v];
    int lanebase = lane & ~15;
    float esv = ES[(size_t)v * HID + c];
    float e2 = 0.0f;
#pragma unroll
    for (int k = 0; k < EDGE_C; ++k)
        e2 += __shfl(esv, lanebase + k, 64) * we[k];
    float h = fmaxf(dv * (s2 + a2[(size_t)v * HID + c] + e2), 0.0f);
    if (slot == 0) h2[(size_t)v * HID + c] = h;
}

// One block per graph: binary-search sorted batch for [start,end), LDS-reduce, 16x8 head.
__global__ void pool_final_kernel(const float* __restrict__ h2,
                                  const int* __restrict__ batch,
                                  const float* __restrict__ W, const float* __restrict__ b,
                                  float* __restrict__ out, int n) {
    __shared__ float sdata[256];
    int g = blockIdx.x;
    int t = threadIdx.x;
    int c = t & 15;
    int lo = 0, hi = n;
    while (lo < hi) { int m = (lo + hi) >> 1; if (batch[m] < g) lo = m + 1; else hi = m; }
    int start = lo;
    hi = n;
    while (lo < hi) { int m = (lo + hi) >> 1; if (batch[m] < g + 1) lo = m + 1; else hi = m; }
    int end = lo;
    float acc = 0.0f;
    for (int v = start + (t >> 4); v < end; v += 16)
        acc += h2[(size_t)v * HID + c];
    sdata[t] = acc; __syncthreads();
    for (int s = 128; s >= 16; s >>= 1) {
        if (t < s) sdata[t] += sdata[t + s];
        __syncthreads();
    }
    if (t < OUT_C) {
        float inv = 1.0f / fmaxf((float)(end - start), 1.0f);
        float o = b[t];
#pragma unroll
        for (int cc = 0; cc < HID; ++cc)
            o += sdata[cc] * inv * W[cc * OUT_C + t];
        out[g * OUT_C + t] = o;
    }
}

// ---------------------------------------------------------------------------
extern "C" void kernel_launch(void* const* d_in, const int* in_sizes, int n_in,
                              void* d_out, int out_size, void* d_ws, size_t ws_size,
                              hipStream_t stream) {
    const float* x         = (const float*)d_in[0];
    const int*   edge_idx  = (const int*)d_in[1];
    const float* edge_attr = (const float*)d_in[2];
    const int*   batch     = (const int*)d_in[3];
    const float* W1_node   = (const float*)d_in[4];
    const float* W1_edge   = (const float*)d_in[5];
    const float* W2_node   = (const float*)d_in[6];
    const float* W2_edge   = (const float*)d_in[7];
    const float* node_W    = (const float*)d_in[8];
    const float* node_b    = (const float*)d_in[9];
    float* out = (float*)d_out;

    const int N = in_sizes[0] / IN_C;
    const int E = in_sizes[1] / 2;
    const int* src = edge_idx;
    const int* dst = edge_idx + E;

    // Workspace layout (adj first for 8B alignment):
    char* p = (char*)d_ws;
    int2*  adj       = (int2*)p;   p += sizeof(int2) * (size_t)E;
    int*   deg       = (int*)p;    p += sizeof(int) * (size_t)N;   // zeroed
    int*   row_start = (int*)p;    p += sizeof(int) * (size_t)N;
    int*   cursor    = (int*)p;    p += sizeof(int) * (size_t)N;
    int*   blocksum  = (int*)p;    p += sizeof(int) * 512;
    float* dinv      = (float*)p;  p += sizeof(float) * (size_t)N;
    float* a1        = (float*)p;  p += sizeof(float) * (size_t)HID * N;
    float* a2        = (float*)p;  p += sizeof(float) * (size_t)HID * N;
    float* ES        = (float*)p;  p += sizeof(float) * (size_t)HID * N;
    float* h2        = a1;         // a1 dead after gather1

    hipMemsetAsync(deg, 0, sizeof(int) * (size_t)N, stream);

    const int tb = 256;
    const int nbN = (N + 255) / 256;
    deg_kernel <<<(E + tb - 1) / tb, tb, 0, stream>>>(dst, deg, E);
    scanA_kernel<<<nbN, 256, 0, stream>>>(deg, row_start, blocksum, N);
    scanB_kernel<<<1, 512, 0, stream>>>(blocksum, nbN);
    scanC_kernel<<<nbN, 256, 0, stream>>>(deg, row_start, blocksum, cursor, dinv, N);

    const int range_size = (N + NRANGE - 1) / NRANGE;
    const int bpr = 256;                       // blocks per range -> 2048 blocks total
    fill_kernel<<<NRANGE * bpr, tb, 0, stream>>>(src, dst, cursor, adj, E, range_size, bpr);

    xform1_kernel<<<(N + 15) / 16, tb, 0, stream>>>(x, W1_node, dinv, a1, N);

    gather1_kernel<<<(N + 3) / 4, tb, 0, stream>>>(
        adj, row_start, deg, edge_attr, W1_edge, W2_node, a1, dinv, a2, ES, N);
    gather2_kernel<<<(N + 3) / 4, tb, 0, stream>>>(
        adj, row_start, deg, W2_edge, a2, dinv, ES, h2, N);

    pool_final_kernel<<<NG, 256, 0, stream>>>(h2, batch, node_W, node_b, out, N);
}